// Round 5
// baseline (314.766 us; speedup 1.0000x reference)
//
#include <hip/hip_runtime.h>
#include <math.h>

#define NUM_K   1024
#define CDIM    64
#define HW      1024          // 32*32
#define NROWS   65536         // 64*1024
#define CHUNK   64            // codes per LDS chunk (16 KB)
#define NCHUNK  (NUM_K / CHUNK)
#define RPT     2             // rows per thread
#define RPB     128           // rows per block = 64 lanes * RPT
#define NBLK    (NROWS / RPB) // 512 blocks -> 2 per CU

// numpy pairwise_sum order for n=64 contiguous fp32 (8 stride-8 chains,
// ((r0+r1)+(r2+r3))+((r4+r5)+(r6+r7))), squares rounded separately (no FMA).
__device__ __forceinline__ float np_sumsq64(const float* a) {
#pragma clang fp contract(off)
  float r0 = a[0]*a[0], r1 = a[1]*a[1], r2 = a[2]*a[2], r3 = a[3]*a[3];
  float r4 = a[4]*a[4], r5 = a[5]*a[5], r6 = a[6]*a[6], r7 = a[7]*a[7];
#pragma unroll
  for (int i = 8; i < 64; i += 8) {
    r0 += a[i+0]*a[i+0]; r1 += a[i+1]*a[i+1];
    r2 += a[i+2]*a[i+2]; r3 += a[i+3]*a[i+3];
    r4 += a[i+4]*a[i+4]; r5 += a[i+5]*a[i+5];
    r6 += a[i+6]*a[i+6]; r7 += a[i+7]*a[i+7];
  }
  return ((r0+r1)+(r2+r3))+((r4+r5)+(r6+r7));
}

// async global->LDS, 16 B per lane (wave-uniform base + lane*16 pattern)
typedef const __attribute__((address_space(1))) unsigned int* glds_gp;
typedef __attribute__((address_space(3))) unsigned int* glds_lp;
__device__ __forceinline__ void load_lds16(const void* g, void* l) {
  __builtin_amdgcn_global_load_lds((glds_gp)g, (glds_lp)l, 16, 0, 0);
}

__device__ __forceinline__ void stage_chunk(const float* __restrict__ emb,
                                            float* e_dst, int cb, int t) {
  const float4* g = (const float4*)(emb + (size_t)cb * CDIM);
  float4* l = (float4*)e_dst;
#pragma unroll
  for (int i = 0; i < (CHUNK * CDIM / 4) / 256; ++i)   // 4 per thread
    load_lds16(g + t + 256 * i, l + t + 256 * i);
}

// launch_bounds(256,1): allocator budget 256 VGPR (empirical: min-waves 2 -> 128
// cap caused R4's spills). Need ~175: x0[64]+x1[64]=128 + e 8 + acc 4 + misc.
// 2 blocks/CU (grid 512), LDS ~46 KB/block. LDS-broadcast roof: 32768 reads/CU
// x 6.4 cy = 87 us; scalar-fmaf VALU = 55 us underneath.
__global__ __launch_bounds__(256, 1)
void vq_main(const float* __restrict__ xin, const float* __restrict__ emb,
             float* __restrict__ out0, float* __restrict__ out_idx,
             float* __restrict__ out_loss, float* __restrict__ out_perp,
             double* __restrict__ partials, unsigned int* __restrict__ counts,
             unsigned int* __restrict__ ticket)
{
  __shared__ float e_s[2 * CHUNK * CDIM];   // 32 KB double-buffered
  __shared__ float nk_all[NUM_K];           // 4 KB (all norms resident)
  __shared__ unsigned int hist_s[NUM_K];    // 4 KB
  __shared__ float dmin_s[3 * RPB];         // 1.5 KB
  __shared__ int   kmin_s[3 * RPB];         // 1.5 KB
  __shared__ double shd[256];               // 2 KB (last-block reduce)
  __shared__ int flag_s;

  const int t  = threadIdx.x;
  const int p  = __builtin_amdgcn_readfirstlane(t >> 6);  // k-parity wave
  const int r  = t & 63;
  const int n0 = blockIdx.x * RPB;
  const int b  = n0 >> 10;                  // 128 | 1024 -> same b for block
  const int hw0 = (n0 & (HW - 1)) + r;

  for (int i = t; i < NUM_K; i += 256) hist_s[i] = 0;

  stage_chunk(emb, e_s, 0, t);              // prefetch chunk 0 (async)

  // fused norms: every block computes all 1024 ||e_k||^2 (np order, L2-hot)
#pragma unroll
  for (int i = 0; i < 4; ++i) {
    const int k = t + 256 * i;
    nk_all[k] = np_sumsq64(emb + (size_t)k * CDIM);
  }

  // gather 2 rows per lane from BHWC (coalesced across lanes per c)
  const float* xb = xin + (size_t)b * (CDIM * HW);
  float x0[CDIM], x1[CDIM];
#pragma unroll
  for (int c = 0; c < CDIM; ++c) {
    x0[c] = xb[(c << 10) + hw0];
    x1[c] = xb[(c << 10) + hw0 + 64];
  }
  const float S0 = np_sumsq64(x0);   // bit-match of np.sum(x*x, axis=1)
  const float S1 = np_sumsq64(x1);

  float dm0 = INFINITY, dm1 = INFINITY;
  int   km0 = 0, km1 = 0;

  __syncthreads();   // chunk 0 staged; nk_all ready

  for (int ci = 0; ci < NCHUNK; ++ci) {
    if (ci + 1 < NCHUNK)
      stage_chunk(emb, e_s + ((ci + 1) & 1) * (CHUNK * CDIM),
                  (ci + 1) * CHUNK, t);

    const float* es = e_s + (ci & 1) * (CHUNK * CDIM);
    const int cb = ci * CHUNK;

    for (int g = 0; g < CHUNK / 8; ++g) {   // 2 k's in flight: 8g+p, 8g+4+p
      const int kl0 = 8 * g + p;
      const int kl1 = kl0 + 4;
      const float4* e0p = (const float4*)(es + kl0 * CDIM);
      const float4* e1p = (const float4*)(es + kl1 * CDIM);
      const float nk0 = nk_all[cb + kl0];
      const float nk1 = nk_all[cb + kl1];
      // 4 independent c-ascending fmaf chains (2 k x 2 rows), each bit-exact
      float d00 = 0.f, d01 = 0.f, d10 = 0.f, d11 = 0.f;
#pragma unroll
      for (int c4 = 0; c4 < 16; ++c4) {
        const float4 a0 = e0p[c4];          // broadcast b128 serves 2 rows
        const float4 a1 = e1p[c4];
        const float p00 = x0[4*c4+0], p01 = x0[4*c4+1];
        const float p02 = x0[4*c4+2], p03 = x0[4*c4+3];
        const float p10 = x1[4*c4+0], p11 = x1[4*c4+1];
        const float p12 = x1[4*c4+2], p13 = x1[4*c4+3];
        d00 = fmaf(p00, a0.x, d00); d01 = fmaf(p10, a0.x, d01);
        d10 = fmaf(p00, a1.x, d10); d11 = fmaf(p10, a1.x, d11);
        d00 = fmaf(p01, a0.y, d00); d01 = fmaf(p11, a0.y, d01);
        d10 = fmaf(p01, a1.y, d10); d11 = fmaf(p11, a1.y, d11);
        d00 = fmaf(p02, a0.z, d00); d01 = fmaf(p12, a0.z, d01);
        d10 = fmaf(p02, a1.z, d10); d11 = fmaf(p12, a1.z, d11);
        d00 = fmaf(p03, a0.w, d00); d01 = fmaf(p13, a0.w, d01);
        d10 = fmaf(p03, a1.w, d10); d11 = fmaf(p13, a1.w, d11);
      }
      // q = fl(fl(S-2d)+nk); 2d exact so fma contraction is bit-identical
      const float q00 = (S0 - 2.0f * d00) + nk0;
      const float q01 = (S1 - 2.0f * d01) + nk0;
      const float q10 = (S0 - 2.0f * d10) + nk1;
      const float q11 = (S1 - 2.0f * d11) + nk1;
      const int kg0 = cb + kl0, kg1 = cb + kl1;
      if (q00 < dm0) { dm0 = q00; km0 = kg0; }
      if (q01 < dm1) { dm1 = q01; km1 = kg0; }
      if (q10 < dm0) { dm0 = q10; km0 = kg1; }
      if (q11 < dm1) { dm1 = q11; km1 = kg1; }
    }
    __syncthreads();
  }

  // lexicographic (d,k) merge across the 4 parities = np first-min semantics
  if (p != 0) {
    dmin_s[(p - 1) * RPB +  0 + r] = dm0;  kmin_s[(p - 1) * RPB +  0 + r] = km0;
    dmin_s[(p - 1) * RPB + 64 + r] = dm1;  kmin_s[(p - 1) * RPB + 64 + r] = km1;
  }
  __syncthreads();
  if (p == 0) {
    float dmv2[RPT] = {dm0, dm1};
    int   kmv2[RPT] = {km0, km1};
    double sd = 0.0;
#pragma unroll
    for (int j = 0; j < RPT; ++j) {
      float dmin = dmv2[j];
      int   kmin = kmv2[j];
#pragma unroll
      for (int q = 0; q < 3; ++q) {
        const float dq = dmin_s[q * RPB + 64 * j + r];
        const int   kq = kmin_s[q * RPB + 64 * j + r];
        if (dq < dmin || (dq == dmin && kq < kmin)) { dmin = dq; kmin = kq; }
      }
      const int n = n0 + 64 * j + r;
      out_idx[n] = (float)kmin;
      atomicAdd(&hist_s[kmin], 1u);

      const float* xj = (j == 0) ? x0 : x1;   // unrolled -> register-resolved
      const float4* eb = (const float4*)(emb + (size_t)kmin * CDIM);
      float4* o = (float4*)(out0 + (size_t)n * CDIM);
      float ssq = 0.f;
#pragma unroll
      for (int c4 = 0; c4 < 16; ++c4) {
        const float4 q4 = eb[c4];
        const float a0 = xj[4*c4+0], a1 = xj[4*c4+1];
        const float a2 = xj[4*c4+2], a3 = xj[4*c4+3];
        const float u0 = q4.x - a0, u1 = q4.y - a1;
        const float u2 = q4.z - a2, u3 = q4.w - a3;
        ssq = fmaf(u0, u0, fmaf(u1, u1, fmaf(u2, u2, fmaf(u3, u3, ssq))));
        o[c4] = make_float4(a0 + u0, a1 + u1, a2 + u2, a3 + u3);
      }
      sd += (double)ssq;
    }
#pragma unroll
    for (int off = 32; off > 0; off >>= 1) sd += __shfl_down(sd, off, 64);
    if (r == 0) partials[blockIdx.x] = sd;
  }
  __syncthreads();
  for (int i = t; i < NUM_K; i += 256) {
    const unsigned int v = hist_s[i];
    if (v) atomicAdd(&counts[i], v);
  }

  // ---- last-block finalization (replaces a second kernel launch) ----
  __threadfence();          // release this block's stores/atomics device-wide
  __syncthreads();
  if (t == 0) {
    const unsigned int old = atomicAdd(ticket, 1u);
    flag_s = (old == NBLK - 1);
  }
  __syncthreads();
  if (!flag_s) return;
  __threadfence();          // acquire

  volatile const double* vp = partials;
  volatile const unsigned int* vc = counts;
  double acc = 0.0, ent = 0.0;
  for (int i = t; i < NBLK; i += 256) acc += vp[i];
  for (int k = t; k < NUM_K; k += 256) {
    const double pr = (double)vc[k] * (1.0 / 65536.0);
    ent += pr * log(pr + 1e-10);
  }
  shd[t] = acc;
  __syncthreads();
  for (int s = 128; s > 0; s >>= 1) { if (t < s) shd[t] += shd[t + s]; __syncthreads(); }
  const double total = shd[0];
  __syncthreads();
  shd[t] = ent;
  __syncthreads();
  for (int s = 128; s > 0; s >>= 1) { if (t < s) shd[t] += shd[t + s]; __syncthreads(); }
  if (t == 0) {
    out_loss[0] = (float)(1.25 * total / 4194304.0);
    out_perp[0] = (float)exp(-shd[0]);
  }
}

extern "C" void kernel_launch(void* const* d_in, const int* in_sizes, int n_in,
                              void* d_out, int out_size, void* d_ws, size_t ws_size,
                              hipStream_t stream)
{
  const float* xin = (const float*)d_in[0];
  const float* emb = (const float*)d_in[1];
  float* out = (float*)d_out;

  // ws: [0,4K) u32 counts | [4K,4K+256) ticket | [8K,12K) f64 partials[512]
  unsigned int* counts   = (unsigned int*)d_ws;
  unsigned int* ticket   = (unsigned int*)((char*)d_ws + 4096);
  double*       partials = (double*)((char*)d_ws + 8192);

  hipMemsetAsync(d_ws, 0, 4096 + 256, stream);   // zero counts + ticket

  float* out0     = out;                       // 4194304 elements (BHWC flat)
  float* out_loss = out + 4194304;             // scalar
  float* out_idx  = out + 4194305;             // 65536 elements (as float)
  float* out_perp = out + 4194305 + 65536;     // scalar

  vq_main<<<dim3(NBLK), dim3(256), 0, stream>>>(xin, emb, out0, out_idx,
                                                out_loss, out_perp,
                                                partials, counts, ticket);
}

// Round 6
// 243.694 us; speedup vs baseline: 1.2916x; 1.2916x over previous
//
#include <hip/hip_runtime.h>
#include <math.h>

#define NUM_K   1024
#define CDIM    64
#define HW      1024            // 32*32
#define NROWS   65536
#define RPB     256             // rows per block
#define NBLK    (NROWS / RPB)   // 256 blocks -> 1 per CU
#define NTHR    512             // 8 waves
#define KCH     128             // codes per staged chunk (32 KB)
#define NCH     (NUM_K / KCH)   // 8
#define KPW     (KCH / 8)       // 16 codes per wave per chunk

// numpy pairwise_sum order for n=64 contiguous fp32 (8 stride-8 chains,
// ((r0+r1)+(r2+r3))+((r4+r5)+(r6+r7))), squares rounded separately (no FMA).
__device__ __forceinline__ float np_sumsq64(const float* a) {
#pragma clang fp contract(off)
  float r0 = a[0]*a[0], r1 = a[1]*a[1], r2 = a[2]*a[2], r3 = a[3]*a[3];
  float r4 = a[4]*a[4], r5 = a[5]*a[5], r6 = a[6]*a[6], r7 = a[7]*a[7];
#pragma unroll
  for (int i = 8; i < 64; i += 8) {
    r0 += a[i+0]*a[i+0]; r1 += a[i+1]*a[i+1];
    r2 += a[i+2]*a[i+2]; r3 += a[i+3]*a[i+3];
    r4 += a[i+4]*a[i+4]; r5 += a[i+5]*a[i+5];
    r6 += a[i+6]*a[i+6]; r7 += a[i+7]*a[i+7];
  }
  return ((r0+r1)+(r2+r3))+((r4+r5)+(r6+r7));
}

// async global->LDS, 16 B per lane (wave-uniform base + lane*16 pattern)
typedef const __attribute__((address_space(1))) unsigned int* glds_gp;
typedef __attribute__((address_space(3))) unsigned int* glds_lp;
__device__ __forceinline__ void load_lds16(const void* g, void* l) {
  __builtin_amdgcn_global_load_lds((glds_gp)g, (glds_lp)l, 16, 0, 0);
}

// 256 blocks x 512 threads (8 waves = 2/SIMD). x-tile in LDS [c4][row]
// (lane-contiguous b128, conflict-free); e in 32 KB double-buffered chunks
// (broadcast b128). Register tile: 4 rows x 16 k fp32 acc (64 VGPRs,
// constant-indexed) -> 256 FMAs per (4 distinct + 16 broadcast) LDS reads.
// LDS roof ~154k cy/CU = 64 us; VALU ~139k cy/SIMD = 58 us.
__global__ __launch_bounds__(NTHR, 1)
void vq_main(const float* __restrict__ xin, const float* __restrict__ emb,
             float* __restrict__ out0, float* __restrict__ out_idx,
             float* __restrict__ out_loss, float* __restrict__ out_perp,
             double* __restrict__ partials, unsigned int* __restrict__ counts,
             unsigned int* __restrict__ ticket)
{
  __shared__ float4 x_s[16 * RPB];          // 64 KB  [c4][row]
  __shared__ float4 e_s[2 * KCH * 16];      // 64 KB  dbuf [code][c4]
  __shared__ float  nk_all[NUM_K];          // 4 KB
  __shared__ unsigned int hist_s[NUM_K];    // 4 KB
  __shared__ float  dmg_s[7 * RPB];         // 7 KB
  __shared__ int    kmg_s[7 * RPB];         // 7 KB
  __shared__ int    kminM[RPB];             // 1 KB
  __shared__ double shd[NTHR];              // 4 KB
  __shared__ int    flag_s;

  const int t = threadIdx.x;
  const int w = __builtin_amdgcn_readfirstlane(t >> 6);  // wave id 0..7
  const int l = t & 63;
  const int n0  = blockIdx.x * RPB;
  const int b   = n0 >> 10;                 // 256 | 1024 -> uniform per block
  const int hwb = n0 & (HW - 1);

  // stage chunk 0 (async DMA overlaps the gather below)
  {
    const float4* g = (const float4*)emb;
#pragma unroll
    for (int i = 0; i < 4; ++i)
      load_lds16(g + t + NTHR * i, &e_s[t + NTHR * i]);
  }

  for (int i = t; i < NUM_K; i += NTHR) hist_s[i] = 0;

  // fused codebook norms (np pairwise order), 2 per thread, from global (L2)
#pragma unroll
  for (int i = 0; i < 2; ++i) {
    const int k = t + NTHR * i;
    nk_all[k] = np_sumsq64(emb + (size_t)k * CDIM);
  }

  // gather x tile: thread t -> row = t&255, c = (t>>8) + 2*i (coalesced reads)
  {
    const int row = t & 255;
    const int ch0 = t >> 8;
    const float* xb = xin + (size_t)b * (CDIM * HW) + hwb + row;
#pragma unroll
    for (int i = 0; i < 32; ++i) {
      const int c = ch0 + 2 * i;
      ((float*)x_s)[(c >> 2) * (RPB * 4) + row * 4 + (c & 3)] = xb[c << 10];
    }
  }
  __syncthreads();   // x_s, nk_all, hist ready; chunk0 staged (barrier drains)

  // per-lane S for its 4 rows (np pairwise order, bit-exact)
  float S[4];
#pragma unroll
  for (int j = 0; j < 4; ++j) {
    const int row = 64 * j + l;
    float4 tmp[16];
#pragma unroll
    for (int c4 = 0; c4 < 16; ++c4) tmp[c4] = x_s[c4 * RPB + row];
    S[j] = np_sumsq64((const float*)tmp);
  }

  float dm[4] = {INFINITY, INFINITY, INFINITY, INFINITY};
  int   km[4] = {0, 0, 0, 0};

  for (int g = 0; g < NCH; ++g) {
    if (g + 1 < NCH) {   // prefetch next chunk into other buffer (no wait)
      const float4* gp = (const float4*)(emb + (size_t)(g + 1) * KCH * CDIM);
      float4* lp = &e_s[((g + 1) & 1) * (KCH * 16)];
#pragma unroll
      for (int i = 0; i < 4; ++i)
        load_lds16(gp + t + NTHR * i, &lp[t + NTHR * i]);
    }

    const float4* eb = &e_s[(g & 1) * (KCH * 16) + (KPW * w) * 16];
    float acc[4][KPW];
#pragma unroll
    for (int j = 0; j < 4; ++j)
#pragma unroll
      for (int kt = 0; kt < KPW; ++kt) acc[j][kt] = 0.f;

#pragma unroll 4
    for (int c4 = 0; c4 < 16; ++c4) {
      float4 xv[4];
#pragma unroll
      for (int j = 0; j < 4; ++j) xv[j] = x_s[c4 * RPB + 64 * j + l];
#pragma unroll
      for (int kt = 0; kt < KPW; ++kt) {
        const float4 ev = eb[kt * 16 + c4];   // broadcast b128
#pragma unroll
        for (int j = 0; j < 4; ++j) {
          acc[j][kt] = fmaf(xv[j].x, ev.x, acc[j][kt]);
          acc[j][kt] = fmaf(xv[j].y, ev.y, acc[j][kt]);
          acc[j][kt] = fmaf(xv[j].z, ev.z, acc[j][kt]);
          acc[j][kt] = fmaf(xv[j].w, ev.w, acc[j][kt]);
        }
      }
    }
    // q = fl(fl(S-2d)+nk); ascending k within wave, strict <
    const int kb = g * KCH + KPW * w;
#pragma unroll
    for (int kt = 0; kt < KPW; ++kt) {
      const float nk = nk_all[kb + kt];
#pragma unroll
      for (int j = 0; j < 4; ++j) {
        const float q = (S[j] - 2.0f * acc[j][kt]) + nk;
        if (q < dm[j]) { dm[j] = q; km[j] = kb + kt; }
      }
    }
    __syncthreads();   // cur buf consumed; next chunk's DMA drained
  }

  // lexicographic (d,k) merge across 8 waves = np first-min semantics
  if (w != 0) {
#pragma unroll
    for (int j = 0; j < 4; ++j) {
      dmg_s[(w - 1) * RPB + 64 * j + l] = dm[j];
      kmg_s[(w - 1) * RPB + 64 * j + l] = km[j];
    }
  }
  __syncthreads();
  if (w == 0) {
#pragma unroll
    for (int j = 0; j < 4; ++j) {
      float dmin = dm[j]; int kmin = km[j];
#pragma unroll
      for (int q = 0; q < 7; ++q) {
        const float dq = dmg_s[q * RPB + 64 * j + l];
        const int   kq = kmg_s[q * RPB + 64 * j + l];
        if (dq < dmin || (dq == dmin && kq < kmin)) { dmin = dq; kmin = kq; }
      }
      kminM[64 * j + l] = kmin;
    }
  }
  __syncthreads();

  // distributed epilogue: 2 threads per row (half-row each)
  {
    const int row  = t & 255;
    const int half = t >> 8;
    const int kk = kminM[row];
    const int n  = n0 + row;
    if (half == 0) {
      out_idx[n] = (float)kk;
      atomicAdd(&hist_s[kk], 1u);
    }
    const float4* ebg = (const float4*)(emb + (size_t)kk * CDIM) + half * 8;
    float4* o = (float4*)(out0 + (size_t)n * CDIM) + half * 8;
    float ssq = 0.f;
#pragma unroll
    for (int i = 0; i < 8; ++i) {
      const float4 q4 = ebg[i];
      const float4 xv = x_s[(half * 8 + i) * RPB + row];
      const float u0 = q4.x - xv.x, u1 = q4.y - xv.y;
      const float u2 = q4.z - xv.z, u3 = q4.w - xv.w;
      ssq = fmaf(u0, u0, fmaf(u1, u1, fmaf(u2, u2, fmaf(u3, u3, ssq))));
      o[i] = make_float4(xv.x + u0, xv.y + u1, xv.z + u2, xv.w + u3);
    }
    shd[t] = (double)ssq;
  }
  __syncthreads();
  for (int s = 256; s > 0; s >>= 1) {
    if (t < s) shd[t] += shd[t + s];
    __syncthreads();
  }
  if (t == 0) partials[blockIdx.x] = shd[0];
  for (int i = t; i < NUM_K; i += NTHR) {
    const unsigned int v = hist_s[i];
    if (v) atomicAdd(&counts[i], v);
  }

  // ---- last-block finalization ----
  __threadfence();
  __syncthreads();
  if (t == 0) {
    const unsigned int old = atomicAdd(ticket, 1u);
    flag_s = (old == NBLK - 1);
  }
  __syncthreads();
  if (!flag_s) return;
  __threadfence();

  volatile const double* vp = partials;
  volatile const unsigned int* vc = counts;
  double acc = 0.0, ent = 0.0;
  for (int i = t; i < NBLK; i += NTHR) acc += vp[i];
  for (int k = t; k < NUM_K; k += NTHR) {
    const double pr = (double)vc[k] * (1.0 / 65536.0);
    ent += pr * log(pr + 1e-10);
  }
  shd[t] = acc;
  __syncthreads();
  for (int s = 256; s > 0; s >>= 1) { if (t < s) shd[t] += shd[t + s]; __syncthreads(); }
  const double total = shd[0];
  __syncthreads();
  shd[t] = ent;
  __syncthreads();
  for (int s = 256; s > 0; s >>= 1) { if (t < s) shd[t] += shd[t + s]; __syncthreads(); }
  if (t == 0) {
    out_loss[0] = (float)(1.25 * total / 4194304.0);
    out_perp[0] = (float)exp(-shd[0]);
  }
}

extern "C" void kernel_launch(void* const* d_in, const int* in_sizes, int n_in,
                              void* d_out, int out_size, void* d_ws, size_t ws_size,
                              hipStream_t stream)
{
  const float* xin = (const float*)d_in[0];
  const float* emb = (const float*)d_in[1];
  float* out = (float*)d_out;

  // ws: [0,4K) u32 counts | [4K,4K+4) ticket | [8K,10K) f64 partials[256]
  unsigned int* counts   = (unsigned int*)d_ws;
  unsigned int* ticket   = (unsigned int*)((char*)d_ws + 4096);
  double*       partials = (double*)((char*)d_ws + 8192);

  hipMemsetAsync(d_ws, 0, 4096 + 256, stream);   // zero counts + ticket

  float* out0     = out;                       // 4194304 elements (BHWC flat)
  float* out_loss = out + 4194304;             // scalar
  float* out_idx  = out + 4194305;             // 65536 elements (as float)
  float* out_perp = out + 4194305 + 65536;     // scalar

  vq_main<<<dim3(NBLK), dim3(NTHR), 0, stream>>>(xin, emb, out0, out_idx,
                                                 out_loss, out_perp,
                                                 partials, counts, ticket);
}